// Round 6
// baseline (42.710 us; speedup 1.0000x reference)
//
#include <hip/hip_runtime.h>

#define MARGIN 0.2f
#define EPSF   1e-16f

constexpr int BSZ  = 512;   // batch
constexpr int DIM  = 1024;  // embedding dim
constexpr int PMAX = 24;    // max positives per anchor (Binom(511,1/128): mean 4, 24 = +10 sigma)

typedef __attribute__((ext_vector_type(8))) short    bf16x8;
typedef __attribute__((ext_vector_type(4))) unsigned uint4v;
typedef __attribute__((ext_vector_type(4))) float    f32x4;

// 8x f32 -> 8x bf16 via v_cvt_pk_bf16_f32 (RNE). A and B use the same packing;
// dot products are k-permutation invariant, so in-lane order is free.
__device__ __forceinline__ bf16x8 cvt8(float4 a, float4 b) {
    uint4v u;
    asm("v_cvt_pk_bf16_f32 %0, %1, %2" : "=v"(u[0]) : "v"(a.x), "v"(a.y));
    asm("v_cvt_pk_bf16_f32 %0, %1, %2" : "=v"(u[1]) : "v"(a.z), "v"(a.w));
    asm("v_cvt_pk_bf16_f32 %0, %1, %2" : "=v"(u[2]) : "v"(b.x), "v"(b.y));
    asm("v_cvt_pk_bf16_f32 %0, %1, %2" : "=v"(u[3]) : "v"(b.z), "v"(b.w));
    return __builtin_bit_cast(bf16x8, u);
}

// ---------------- Node 1: fused GEMM tile + in-block posvals + hinge epilogue
// 256 blocks x 4 waves. brow = blk>>3 (16-anchor strip), bcol = blk&7;
// wave w owns C tile [tr..tr+16) x [tc..tc+16), tc = bcol*64 + w*16.
// Per block (redundant per row-strip, cheap): posvals[al][i] = f32 dot of
// img[tr+al] with sen[p] for each positive p (ballot-ordered, deterministic).
// mfma_f32_16x16x32_bf16: A/B row|col = lane&15, k = (lane>>4)*8 + j;
// C/D: col = lane&15, row = (lane>>4)*4 + q.
__global__ void __launch_bounds__(256) fused_gemm_triplet(const float* __restrict__ I,
                                                          const float* __restrict__ S,
                                                          const int*   __restrict__ labels,
                                                          float* __restrict__ psum,
                                                          float* __restrict__ pcnt) {
    __shared__ int   lab_s[BSZ];
    __shared__ int   pos_p[16][PMAX];
    __shared__ float pv_s[16][PMAX];
    __shared__ int   np_s[16];
    __shared__ float wsum_s[4];
    __shared__ int   wcnt_s[4];

    const int tid  = threadIdx.x;
    const int lane = tid & 63;
    const int w    = tid >> 6;
    const int brow = blockIdx.x >> 3;        // 0..31
    const int bcol = blockIdx.x & 7;         // 0..7
    const int tr   = brow * 16;
    const int tc   = bcol * 64 + w * 16;

    lab_s[tid]       = labels[tid];
    lab_s[tid + 256] = labels[tid + 256];
    __syncthreads();

    // ---- Phase 1a: ballot-built positive lists (wave w -> anchors w*4..w*4+3)
#pragma unroll
    for (int al0 = 0; al0 < 4; ++al0) {
        const int al = w * 4 + al0;
        const int la = lab_s[tr + al];
        int npos = 0;
        for (int p0 = 0; p0 < BSZ; p0 += 64) {
            const bool isp = (lab_s[p0 + lane] == la);
            const unsigned long long m = __ballot(isp);
            if (isp) {
                const int idx = npos + __popcll(m & ((1ull << lane) - 1ull));
                if (idx < PMAX) pos_p[al][idx] = p0 + lane;
            }
            npos += __popcll(m);
        }
        if (lane == 0) np_s[al] = (npos < PMAX) ? npos : PMAX;
    }

    // ---- Phase 2: MFMA GEMM main loop (loads issue first, hide everything)
    const int r  = lane & 15;
    const int hi = lane >> 4;
    const int kb = hi * 8;                   // k offset (floats)
    const float4* Af = (const float4*)(I + (size_t)(tr + r) * DIM + kb);
    const float4* Bf = (const float4*)(S + (size_t)(tc + r) * DIM + kb);

    f32x4 acc0 = {0.f, 0.f, 0.f, 0.f};
    f32x4 acc1 = {0.f, 0.f, 0.f, 0.f};
#pragma unroll
    for (int t = 0; t < DIM / 32; t += 2) {  // 32 k-steps, 2 acc chains
        acc0 = __builtin_amdgcn_mfma_f32_16x16x32_bf16(
                   cvt8(Af[t * 8],     Af[t * 8 + 1]),
                   cvt8(Bf[t * 8],     Bf[t * 8 + 1]), acc0, 0, 0, 0);
        acc1 = __builtin_amdgcn_mfma_f32_16x16x32_bf16(
                   cvt8(Af[t * 8 + 8], Af[t * 8 + 9]),
                   cvt8(Bf[t * 8 + 8], Bf[t * 8 + 9]), acc1, 0, 0, 0);
    }
    acc0 += acc1;

    // ---- Phase 1b: f32 posval dots, 16-lane groups, 4 pairs in flight/wave
    const int g  = lane >> 4;                // group 0..3
    const int gl = lane & 15;                // lane in group
#pragma unroll
    for (int al0 = 0; al0 < 4; ++al0) {
        const int al = w * 4 + al0;
        const int np = np_s[al];
        const float* Ia = I + (size_t)(tr + al) * DIM;
        for (int i0 = 0; i0 < np; i0 += 4) {
            const int i = i0 + g;
            float s = 0.f;
            if (i < np) {
                const float* Sp = S + (size_t)pos_p[al][i] * DIM;
#pragma unroll
                for (int j = 0; j < 16; ++j) {   // 64 floats/lane, fixed order
                    const float4 a4 = *(const float4*)(Ia + j * 64 + gl * 4);
                    const float4 b4 = *(const float4*)(Sp + j * 64 + gl * 4);
                    s += a4.x * b4.x + a4.y * b4.y + a4.z * b4.z + a4.w * b4.w;
                }
            }
            s += __shfl_xor(s, 1);
            s += __shfl_xor(s, 2);
            s += __shfl_xor(s, 4);
            s += __shfl_xor(s, 8);
            if (gl == 0 && i < np) pv_s[al][i] = s;
        }
    }
    __syncthreads();                          // pv_s visible to all waves

    // ---- Phase 3: hinge epilogue on registers: lane holds C[tr+hi*4+q][tc+r]
    const int ln = lab_s[bcol * 64 + w * 16 + r];
    float sum = 0.f;
    int   cnt = 0;
#pragma unroll
    for (int q = 0; q < 4; ++q) {
        const int al = hi * 4 + q;            // local anchor 0..15
        if (ln != lab_s[tr + al]) {           // column is a negative for anchor
            const float c  = acc0[q];
            const int   np = np_s[al];
            for (int i = 0; i < np; ++i) {
                const float v = pv_s[al][i] - c + MARGIN;
                sum += fmaxf(v, 0.f);
                cnt += (v > EPSF) ? 1 : 0;
            }
        }
    }

    // ---- block reduction -> per-block partials (fully written, no init)
#pragma unroll
    for (int off = 32; off > 0; off >>= 1) {
        sum += __shfl_down(sum, off);
        cnt += __shfl_down(cnt, off);
    }
    if (lane == 0) { wsum_s[w] = sum; wcnt_s[w] = cnt; }
    __syncthreads();
    if (tid == 0) {
        psum[blockIdx.x] = wsum_s[0] + wsum_s[1] + wsum_s[2] + wsum_s[3];
        pcnt[blockIdx.x] = (float)(wcnt_s[0] + wcnt_s[1] + wcnt_s[2] + wcnt_s[3]);
    }
}

// ---------------- Node 2: finalize over 256 partials ----------------
__global__ void __launch_bounds__(256) finalize(const float* __restrict__ psum,
                                                const float* __restrict__ pcnt,
                                                float* __restrict__ out) {
    __shared__ float wsum[4], wcnt[4];
    const int tid = threadIdx.x;
    float s = psum[tid];
    float c = pcnt[tid];
#pragma unroll
    for (int off = 32; off > 0; off >>= 1) {
        s += __shfl_down(s, off);
        c += __shfl_down(c, off);
    }
    const int wid = tid >> 6, lane = tid & 63;
    if (lane == 0) { wsum[wid] = s; wcnt[wid] = c; }
    __syncthreads();
    if (tid == 0) {
        const float S_ = wsum[0] + wsum[1] + wsum[2] + wsum[3];
        const float C_ = wcnt[0] + wcnt[1] + wcnt[2] + wcnt[3];
        out[0] = S_ / (C_ + EPSF);
    }
}

extern "C" void kernel_launch(void* const* d_in, const int* in_sizes, int n_in,
                              void* d_out, int out_size, void* d_ws, size_t ws_size,
                              hipStream_t stream) {
    const int*   labels = (const int*)d_in[0];
    const float* img    = (const float*)d_in[1];
    const float* sen    = (const float*)d_in[2];
    float* out = (float*)d_out;

    float* psum = (float*)d_ws;                      // 256 floats
    float* pcnt = (float*)((char*)d_ws + 1024);      // 256 floats

    fused_gemm_triplet<<<256, 256, 0, stream>>>(img, sen, labels, psum, pcnt);
    finalize<<<1, 256, 0, stream>>>(psum, pcnt, out);
}